// Round 1
// baseline (184.382 us; speedup 1.0000x reference)
//
#include <hip/hip_runtime.h>

// EndEffectorLoss: rot6d -> R, FK over fixed 24-joint tree, end-effector MSE.
// Layout: pose [F,24,6] f32, offsets [F,24,3] f32, t_pose [24,3] f32.
// Thread mapping: 2 threads per frame (pose A / pose B), LDS exchange.
// Memory-bound: ~113 MB read -> ~18 us floor at 6.3 TB/s.

struct V3 { float x, y, z; };
struct M3 { float m[3][3]; };   // row r = basis vector b_r (row-stacked)

__device__ __forceinline__ V3 matvec(const M3& A, const V3& v) {
    return { A.m[0][0]*v.x + A.m[0][1]*v.y + A.m[0][2]*v.z,
             A.m[1][0]*v.x + A.m[1][1]*v.y + A.m[1][2]*v.z,
             A.m[2][0]*v.x + A.m[2][1]*v.y + A.m[2][2]*v.z };
}

__device__ __forceinline__ M3 matmul(const M3& A, const M3& B) {
    M3 C;
#pragma unroll
    for (int i = 0; i < 3; i++)
#pragma unroll
        for (int j = 0; j < 3; j++)
            C.m[i][j] = A.m[i][0]*B.m[0][j] + A.m[i][1]*B.m[1][j] + A.m[i][2]*B.m[2][j];
    return C;
}

// Pose joint J: 6 floats at frame + 6J. Frame base is 16B-aligned (f*576B),
// so even J -> 16B aligned (float4+float2), odd J -> 8B aligned (float2+float4).
template<int J>
__device__ __forceinline__ M3 rot6d_j(const float* __restrict__ frame) {
    const float* p = frame + 6 * J;
    float v0, v1, v2, v3, v4, v5;
    if constexpr ((J & 1) == 0) {
        float4 a = *(const float4*)p;
        float2 b = *(const float2*)(p + 4);
        v0 = a.x; v1 = a.y; v2 = a.z; v3 = a.w; v4 = b.x; v5 = b.y;
    } else {
        float2 a = *(const float2*)p;
        float4 b = *(const float4*)(p + 2);
        v0 = a.x; v1 = a.y; v2 = b.x; v3 = b.y; v4 = b.z; v5 = b.w;
    }
    // Gram-Schmidt (matches jnp reference, f32)
    float n1 = v0*v0 + v1*v1 + v2*v2;
    float r1 = 1.0f / sqrtf(n1);
    V3 b1 = { v0*r1, v1*r1, v2*r1 };
    float d = b1.x*v3 + b1.y*v4 + b1.z*v5;
    V3 u = { v3 - d*b1.x, v4 - d*b1.y, v5 - d*b1.z };
    float n2 = u.x*u.x + u.y*u.y + u.z*u.z;
    float r2 = 1.0f / sqrtf(n2);
    V3 b2 = { u.x*r2, u.y*r2, u.z*r2 };
    V3 b3 = { b1.y*b2.z - b1.z*b2.y, b1.z*b2.x - b1.x*b2.z, b1.x*b2.y - b1.y*b2.x };
    M3 R;
    R.m[0][0]=b1.x; R.m[0][1]=b1.y; R.m[0][2]=b1.z;
    R.m[1][0]=b2.x; R.m[1][1]=b2.y; R.m[1][2]=b2.z;
    R.m[2][0]=b3.x; R.m[2][1]=b3.y; R.m[2][2]=b3.z;
    return R;
}

// Offset joint J: 3 floats at obase + 3J. Frame base is 8B-aligned (f*288B):
// even J -> 8B aligned (float2+float), odd J -> float + float2 (p+1 is 8B aligned).
template<int J>
__device__ __forceinline__ V3 load_off_j(const float* __restrict__ obase) {
    const float* p = obase + 3 * J;
    if constexpr ((J & 1) == 0) {
        float2 a = *(const float2*)p;
        float  b = p[2];
        return { a.x, a.y, b };
    } else {
        float  a = p[0];
        float2 b = *(const float2*)(p + 1);
        return { a, b.x, b.y };
    }
}

template<int J>
__device__ __forceinline__ void fk_step(const float* __restrict__ frame,
                                        const float* __restrict__ obase,
                                        M3& ori, V3& pos) {
    V3 o = load_off_j<J>(obase);
    V3 t = matvec(ori, o);           // parent orientation
    pos.x += t.x; pos.y += t.y; pos.z += t.z;
    M3 R = rot6d_j<J>(frame);
    ori = matmul(ori, R);
}

template<int J>
__device__ __forceinline__ void fk_end(const float* __restrict__ obase,
                                       const M3& ori, const V3& pos, float* out) {
    V3 o = load_off_j<J>(obase);
    V3 t = matvec(ori, o);
    out[0] = pos.x + t.x; out[1] = pos.y + t.y; out[2] = pos.z + t.z;
}

// DFS over the fixed hierarchy; end sites {10,11,15,22,23} need no rot6d.
__device__ __forceinline__ void fk_ee(const float* __restrict__ frame,
                                      const float* __restrict__ obase,
                                      float ee[15]) {
    M3 ori0 = rot6d_j<0>(frame);
    V3 pos0 = load_off_j<0>(obase);

    M3 ori; V3 pos;
    // chain 0 -> 1 -> 4 -> 7 -> ee 10
    ori = ori0; pos = pos0;
    fk_step<1>(frame, obase, ori, pos);
    fk_step<4>(frame, obase, ori, pos);
    fk_step<7>(frame, obase, ori, pos);
    fk_end<10>(obase, ori, pos, ee + 0);
    // chain 0 -> 2 -> 5 -> 8 -> ee 11
    ori = ori0; pos = pos0;
    fk_step<2>(frame, obase, ori, pos);
    fk_step<5>(frame, obase, ori, pos);
    fk_step<8>(frame, obase, ori, pos);
    fk_end<11>(obase, ori, pos, ee + 3);
    // chain 0 -> 3 -> 6 -> 9 (save), then 12 -> ee 15
    ori = ori0; pos = pos0;
    fk_step<3>(frame, obase, ori, pos);
    fk_step<6>(frame, obase, ori, pos);
    fk_step<9>(frame, obase, ori, pos);
    M3 ori9 = ori; V3 pos9 = pos;
    fk_step<12>(frame, obase, ori, pos);
    fk_end<15>(obase, ori, pos, ee + 6);
    // 9 -> 13 -> 16 -> 18 -> 20 -> ee 22
    ori = ori9; pos = pos9;
    fk_step<13>(frame, obase, ori, pos);
    fk_step<16>(frame, obase, ori, pos);
    fk_step<18>(frame, obase, ori, pos);
    fk_step<20>(frame, obase, ori, pos);
    fk_end<22>(obase, ori, pos, ee + 9);
    // 9 -> 14 -> 17 -> 19 -> 21 -> ee 23
    ori = ori9; pos = pos9;
    fk_step<14>(frame, obase, ori, pos);
    fk_step<17>(frame, obase, ori, pos);
    fk_step<19>(frame, obase, ori, pos);
    fk_step<21>(frame, obase, ori, pos);
    fk_end<23>(obase, ori, pos, ee + 12);
}

__global__ __launch_bounds__(256, 2)
void ee_loss_kernel(const float* __restrict__ poseA, const float* __restrict__ poseB,
                    const float* __restrict__ offA,  const float* __restrict__ offB,
                    const float* __restrict__ tA,    const float* __restrict__ tB,
                    float* __restrict__ out, float inv_count) {
    const int tid  = threadIdx.x;
    const int fl   = tid >> 1;        // frame-local 0..127
    const int pose = tid & 1;         // 0 = A, 1 = B
    const long long f = (long long)blockIdx.x * 128 + fl;

    const float* frame = (pose ? poseB : poseA) + f * 144;
    const float* obase = (pose ? offB  : offA ) + f * 72;

    float ee[15];
    fk_ee(frame, obase, ee);

    __shared__ float s_eeB[128][15];  // rows stride 15 -> conflict-free (gcd(15,32)=1)
    __shared__ float s_inv[6];        // 1/scaleA(xyz), 1/scaleB(xyz)
    __shared__ float s_d[15];         // tB[ee]/sB - tA[ee]/sA
    __shared__ float s_part[4];

    if (pose) {
#pragma unroll
        for (int i = 0; i < 15; i++) s_eeB[fl][i] = ee[i];
    }
    if (tid < 6) {
        const float* tp = (tid < 3) ? tA : tB;
        int ax = (tid < 3) ? tid : tid - 3;
        float mn = tp[ax], mx = mn;
#pragma unroll
        for (int j = 1; j < 24; j++) {
            float v = tp[j*3 + ax];
            mn = fminf(mn, v); mx = fmaxf(mx, v);
        }
        s_inv[tid] = 1.0f / (mx - mn);
    }
    __syncthreads();
    if (tid < 15) {
        const int EE[5] = {10, 11, 15, 22, 23};
        int e = tid / 3, ax = tid - 3*e;
        int j = EE[e];
        s_d[tid] = tB[j*3 + ax]*s_inv[3 + ax] - tA[j*3 + ax]*s_inv[ax];
    }
    __syncthreads();

    float local = 0.0f;
    if (!pose) {
#pragma unroll
        for (int i = 0; i < 15; i++) {
            int ax = i % 3;  // constant after unroll
            float t = ee[i]*s_inv[ax] - s_eeB[fl][i]*s_inv[3 + ax] + s_d[i];
            local += t * t;
        }
        local *= inv_count;
    }
#pragma unroll
    for (int off = 32; off > 0; off >>= 1)
        local += __shfl_down(local, off, 64);
    const int lane = tid & 63, wid = tid >> 6;
    if (lane == 0) s_part[wid] = local;
    __syncthreads();
    if (tid == 0) atomicAdd(out, (s_part[0] + s_part[1]) + (s_part[2] + s_part[3]));
}

extern "C" void kernel_launch(void* const* d_in, const int* in_sizes, int n_in,
                              void* d_out, int out_size, void* d_ws, size_t ws_size,
                              hipStream_t stream) {
    const float* poseA = (const float*)d_in[0];
    const float* poseB = (const float*)d_in[1];
    const float* offA  = (const float*)d_in[2];
    const float* offB  = (const float*)d_in[3];
    const float* tA    = (const float*)d_in[4];
    const float* tB    = (const float*)d_in[5];
    float* out = (float*)d_out;

    const int F = in_sizes[0] / 144;          // 65536
    const int blocks = F / 128;               // 2 threads per frame, 256/block
    const float inv_count = 1.0f / ((float)F * 15.0f);

    hipMemsetAsync(out, 0, sizeof(float), stream);  // d_out is poisoned 0xAA
    ee_loss_kernel<<<blocks, 256, 0, stream>>>(poseA, poseB, offA, offB, tA, tB,
                                               out, inv_count);
}

// Round 2
// 174.985 us; speedup vs baseline: 1.0537x; 1.0537x over previous
//
#include <hip/hip_runtime.h>

// EndEffectorLoss: rot6d -> R, FK over fixed 24-joint tree, end-effector MSE.
// R2: topological-order FK (monotone address streams, minimal live state),
// 4 threads/frame (A/B x short/long subtree) mapped by WAVE id (no divergence).
// pose [F,24,6] f32, offsets [F,24,3] f32, t_pose [24,3] f32. Out: 1 f32.

struct V3 { float x, y, z; };
struct M3 { float m[3][3]; };   // row r = basis vector b_r (row-stacked)

__device__ __forceinline__ V3 matvec(const M3& A, const V3& v) {
    return { A.m[0][0]*v.x + A.m[0][1]*v.y + A.m[0][2]*v.z,
             A.m[1][0]*v.x + A.m[1][1]*v.y + A.m[1][2]*v.z,
             A.m[2][0]*v.x + A.m[2][1]*v.y + A.m[2][2]*v.z };
}

__device__ __forceinline__ M3 matmul(const M3& A, const M3& B) {
    M3 C;
#pragma unroll
    for (int i = 0; i < 3; i++)
#pragma unroll
        for (int j = 0; j < 3; j++)
            C.m[i][j] = A.m[i][0]*B.m[0][j] + A.m[i][1]*B.m[1][j] + A.m[i][2]*B.m[2][j];
    return C;
}

// Pose joint J: 6 floats at frame + 6J; frame base 16B-aligned (576B/frame).
// even J -> 16B aligned (float4+float2); odd J -> 8B (float2 + 16B float4).
template<int J>
__device__ __forceinline__ M3 rot6d_j(const float* __restrict__ frame) {
    const float* p = frame + 6 * J;
    float v0, v1, v2, v3, v4, v5;
    if constexpr ((J & 1) == 0) {
        float4 a = *(const float4*)p;
        float2 b = *(const float2*)(p + 4);
        v0 = a.x; v1 = a.y; v2 = a.z; v3 = a.w; v4 = b.x; v5 = b.y;
    } else {
        float2 a = *(const float2*)p;
        float4 b = *(const float4*)(p + 2);
        v0 = a.x; v1 = a.y; v2 = b.x; v3 = b.y; v4 = b.z; v5 = b.w;
    }
    float n1 = v0*v0 + v1*v1 + v2*v2;
    float r1 = 1.0f / sqrtf(n1);
    V3 b1 = { v0*r1, v1*r1, v2*r1 };
    float d = b1.x*v3 + b1.y*v4 + b1.z*v5;
    V3 u = { v3 - d*b1.x, v4 - d*b1.y, v5 - d*b1.z };
    float n2 = u.x*u.x + u.y*u.y + u.z*u.z;
    float r2 = 1.0f / sqrtf(n2);
    V3 b2 = { u.x*r2, u.y*r2, u.z*r2 };
    V3 b3 = { b1.y*b2.z - b1.z*b2.y, b1.z*b2.x - b1.x*b2.z, b1.x*b2.y - b1.y*b2.x };
    M3 R;
    R.m[0][0]=b1.x; R.m[0][1]=b1.y; R.m[0][2]=b1.z;
    R.m[1][0]=b2.x; R.m[1][1]=b2.y; R.m[1][2]=b2.z;
    R.m[2][0]=b3.x; R.m[2][1]=b3.y; R.m[2][2]=b3.z;
    return R;
}

// Offset joint J: 3 floats at obase + 3J; obase 16B-aligned (288B/frame).
template<int J>
__device__ __forceinline__ V3 load_off_j(const float* __restrict__ obase) {
    const float* p = obase + 3 * J;
    if constexpr ((J & 1) == 0) {
        float2 a = *(const float2*)p;
        float  b = p[2];
        return { a.x, a.y, b };
    } else {
        float  a = p[0];
        float2 b = *(const float2*)(p + 1);
        return { a, b.x, b.y };
    }
}

struct FK { M3 o; V3 p; };

template<int J>
__device__ __forceinline__ FK fk_step(const float* __restrict__ frame,
                                      const float* __restrict__ obase,
                                      const FK& par) {
    V3 off = load_off_j<J>(obase);
    V3 t = matvec(par.o, off);
    FK s;
    s.p = { par.p.x + t.x, par.p.y + t.y, par.p.z + t.z };
    s.o = matmul(par.o, rot6d_j<J>(frame));
    return s;
}

template<int J>
__device__ __forceinline__ V3 fk_end(const float* __restrict__ obase, const FK& par) {
    V3 off = load_off_j<J>(obase);
    V3 t = matvec(par.o, off);
    return { par.p.x + t.x, par.p.y + t.y, par.p.z + t.z };
}

__global__ __launch_bounds__(256, 4)
void ee_loss_kernel(const float* __restrict__ poseA, const float* __restrict__ poseB,
                    const float* __restrict__ offA,  const float* __restrict__ offB,
                    const float* __restrict__ tA,    const float* __restrict__ tB,
                    float* __restrict__ out, float inv_count) {
    const int tid  = threadIdx.x;
    const int wid  = tid >> 6;           // 0:A-short 1:B-short 2:A-long 3:B-long
    const int lane = tid & 63;
    const bool isB    = wid & 1;
    const bool isLong = wid & 2;
    const long long f = (long long)blockIdx.x * 64 + lane;

    const float* frame = (isB ? poseB : poseA) + f * 144;
    const float* obase = (isB ? offB  : offA ) + f * 72;

    __shared__ float s_eeB[64][15];      // stride 15: gcd(15,32)=1, conflict-free
    __shared__ float s_inv[6];           // 1/scaleA(xyz), 1/scaleB(xyz)
    __shared__ float s_d[15];            // tB[ee]/sB - tA[ee]/sA
    __shared__ float s_part[4];

    // t_pose-derived constants (72 floats each, L2-resident; no inter-dependency
    // between s_inv and s_d producers -> single barrier suffices).
    if (tid < 6) {
        const float* tp = (tid < 3) ? tA : tB;
        int ax = (tid < 3) ? tid : tid - 3;
        float mn = tp[ax], mx = mn;
#pragma unroll
        for (int j = 1; j < 24; j++) {
            float v = tp[j*3 + ax];
            mn = fminf(mn, v); mx = fmaxf(mx, v);
        }
        s_inv[tid] = 1.0f / (mx - mn);
    }
    if (tid < 15) {
        const int EE[5] = {10, 11, 15, 22, 23};
        int e = tid / 3, ax = tid - 3*e;
        int j = EE[e];
        float mnA = tA[ax], mxA = mnA, mnB = tB[ax], mxB = mnB;
#pragma unroll
        for (int k = 1; k < 24; k++) {
            float a = tA[k*3 + ax], b = tB[k*3 + ax];
            mnA = fminf(mnA, a); mxA = fmaxf(mxA, a);
            mnB = fminf(mnB, b); mxB = fmaxf(mxB, b);
        }
        s_d[tid] = tB[j*3 + ax]/(mxB - mnB) - tA[j*3 + ax]/(mxA - mnA);
    }

    // FK in topological index order -> strictly ascending addresses per thread.
    float ee[9];
    int nee;
    if (!isLong) {
        // joints 0,1,2,4,5,7,8 -> ee 10,11 (6 values)
        FK r0; r0.o = rot6d_j<0>(frame); r0.p = load_off_j<0>(obase);
        FK a = fk_step<1>(frame, obase, r0);
        FK b = fk_step<2>(frame, obase, r0);
        a = fk_step<4>(frame, obase, a);
        b = fk_step<5>(frame, obase, b);
        a = fk_step<7>(frame, obase, a);
        b = fk_step<8>(frame, obase, b);
        V3 e10 = fk_end<10>(obase, a);
        V3 e11 = fk_end<11>(obase, b);
        ee[0]=e10.x; ee[1]=e10.y; ee[2]=e10.z;
        ee[3]=e11.x; ee[4]=e11.y; ee[5]=e11.z;
        nee = 6;
    } else {
        // joints 0,3,6,9,12,13,14,16..21 -> ee 15,22,23 (9 values)
        FK r0; r0.o = rot6d_j<0>(frame); r0.p = load_off_j<0>(obase);
        FK s = fk_step<3>(frame, obase, r0);
        s = fk_step<6>(frame, obase, s);
        s = fk_step<9>(frame, obase, s);
        FK sa = fk_step<12>(frame, obase, s);
        FK sb = fk_step<13>(frame, obase, s);
        FK sc = fk_step<14>(frame, obase, s);
        V3 e15 = fk_end<15>(obase, sa);
        sb = fk_step<16>(frame, obase, sb);
        sc = fk_step<17>(frame, obase, sc);
        sb = fk_step<18>(frame, obase, sb);
        sc = fk_step<19>(frame, obase, sc);
        sb = fk_step<20>(frame, obase, sb);
        sc = fk_step<21>(frame, obase, sc);
        V3 e22 = fk_end<22>(obase, sb);
        V3 e23 = fk_end<23>(obase, sc);
        ee[0]=e15.x; ee[1]=e15.y; ee[2]=e15.z;
        ee[3]=e22.x; ee[4]=e22.y; ee[5]=e22.z;
        ee[6]=e23.x; ee[7]=e23.y; ee[8]=e23.z;
        nee = 9;
    }

    const int base = isLong ? 6 : 0;     // column base in s_eeB / s_d
    if (isB) {
#pragma unroll 9
        for (int i = 0; i < 9; i++)
            if (i < nee) s_eeB[lane][base + i] = ee[i];
    }
    __syncthreads();

    float local = 0.0f;
    if (!isB) {
#pragma unroll 9
        for (int i = 0; i < 9; i++) {
            if (i < nee) {
                int col = base + i;
                int ax = col % 3;        // constant after unroll
                float t = ee[i]*s_inv[ax] - s_eeB[lane][col]*s_inv[3 + ax] + s_d[col];
                local += t * t;
            }
        }
        local *= inv_count;
    }
#pragma unroll
    for (int off = 32; off > 0; off >>= 1)
        local += __shfl_down(local, off, 64);
    if (lane == 0) s_part[wid] = local;
    __syncthreads();
    if (tid == 0) atomicAdd(out, (s_part[0] + s_part[1]) + (s_part[2] + s_part[3]));
}

extern "C" void kernel_launch(void* const* d_in, const int* in_sizes, int n_in,
                              void* d_out, int out_size, void* d_ws, size_t ws_size,
                              hipStream_t stream) {
    const float* poseA = (const float*)d_in[0];
    const float* poseB = (const float*)d_in[1];
    const float* offA  = (const float*)d_in[2];
    const float* offB  = (const float*)d_in[3];
    const float* tA    = (const float*)d_in[4];
    const float* tB    = (const float*)d_in[5];
    float* out = (float*)d_out;

    const int F = in_sizes[0] / 144;          // 65536
    const int blocks = F / 64;                // 64 frames/block, 4 waves/block
    const float inv_count = 1.0f / ((float)F * 15.0f);

    hipMemsetAsync(out, 0, sizeof(float), stream);
    ee_loss_kernel<<<blocks, 256, 0, stream>>>(poseA, poseB, offA, offB, tA, tB,
                                               out, inv_count);
}